// Round 9
// baseline (2797.450 us; speedup 1.0000x reference)
//
#include <hip/hip_runtime.h>

#define Bz 32
#define Tz 64
#define Sz 128
#define Dz 256
#define Vz 32000
#define NWRK 125   // active logits workers (256-col slice each)

__device__ __forceinline__ float sigmf(float x){ return 1.0f/(1.0f + __expf(-x)); }
__device__ __forceinline__ float tanhfast(float x){ float e = __expf(2.0f*x); return 1.0f - 2.0f/(e+1.0f); }

__device__ __forceinline__ void st_l3(float* p, float v){
  __hip_atomic_store(p, v, __ATOMIC_RELAXED, __HIP_MEMORY_SCOPE_AGENT);
}
__device__ __forceinline__ float ld_l3(const float* p){
  return __hip_atomic_load(p, __ATOMIC_RELAXED, __HIP_MEMORY_SCOPE_AGENT);
}

// ---- K_PREP: keys = enc@Wk+bk ; encW = enc@Wx[0:256] ; embW[b,t] = E[tok]@Wx[256:512] ----
__global__ void __launch_bounds__(256) k_prep(const float* __restrict__ enc,
                                              const float* __restrict__ Wk,
                                              const float* __restrict__ bk,
                                              const float* __restrict__ Wx,
                                              const float* __restrict__ E,
                                              const int* __restrict__ tok,
                                              float* __restrict__ keys,
                                              float* __restrict__ encW,
                                              float* __restrict__ embW,
                                              unsigned* __restrict__ flags){
  const int blk = blockIdx.x, tid = threadIdx.x;
  if (blk == 0 && tid < 160) flags[tid] = 0u;      // 128 flags + 16 ctr (+pad)
  if (blk < 256){
    const int b  = blk >> 3;
    const int s0 = (blk & 7) * 16;
    const float* ebase = enc + (b*Sz + s0)*Dz;
    const int d = tid;
    float acc[16];
    #pragma unroll
    for (int i = 0; i < 16; ++i) acc[i] = 0.f;
    for (int k = 0; k < Dz; k += 4){
      float w0 = Wk[(k+0)*Dz + d], w1 = Wk[(k+1)*Dz + d];
      float w2 = Wk[(k+2)*Dz + d], w3 = Wk[(k+3)*Dz + d];
      #pragma unroll
      for (int si = 0; si < 16; ++si){
        float4 ev = *(const float4*)(ebase + si*Dz + k);
        acc[si] += ev.x*w0 + ev.y*w1 + ev.z*w2 + ev.w*w3;
      }
    }
    const float bkd = bk[d];
    #pragma unroll
    for (int si = 0; si < 16; ++si)
      keys[(b*Sz + s0 + si)*Dz + d] = acc[si] + bkd;
  } else if (blk < 1280){
    const int row0 = (blk - 256) * 4;              // 1024 blocks x 4 rows of enc
    const int u4 = tid * 4;
    float4 a0 = {0,0,0,0}, a1 = {0,0,0,0}, a2 = {0,0,0,0}, a3 = {0,0,0,0};
    for (int d = 0; d < Dz; ++d){
      float4 wv = *(const float4*)(Wx + (size_t)d*1024 + u4);
      float e0 = enc[(size_t)(row0+0)*Dz + d];
      float e1 = enc[(size_t)(row0+1)*Dz + d];
      float e2 = enc[(size_t)(row0+2)*Dz + d];
      float e3 = enc[(size_t)(row0+3)*Dz + d];
      a0.x += e0*wv.x; a0.y += e0*wv.y; a0.z += e0*wv.z; a0.w += e0*wv.w;
      a1.x += e1*wv.x; a1.y += e1*wv.y; a1.z += e1*wv.z; a1.w += e1*wv.w;
      a2.x += e2*wv.x; a2.y += e2*wv.y; a2.z += e2*wv.z; a2.w += e2*wv.w;
      a3.x += e3*wv.x; a3.y += e3*wv.y; a3.z += e3*wv.z; a3.w += e3*wv.w;
    }
    *(float4*)(encW + (size_t)(row0+0)*1024 + u4) = a0;
    *(float4*)(encW + (size_t)(row0+1)*1024 + u4) = a1;
    *(float4*)(encW + (size_t)(row0+2)*1024 + u4) = a2;
    *(float4*)(encW + (size_t)(row0+3)*1024 + u4) = a3;
  } else {
    const int bt0 = (blk - 1280) * 4;              // 512 blocks x 4 (b,t) rows; bt = b*64+t
    const int u4 = tid * 4;
    const float* e0p = E + (size_t)tok[bt0+0]*Dz;
    const float* e1p = E + (size_t)tok[bt0+1]*Dz;
    const float* e2p = E + (size_t)tok[bt0+2]*Dz;
    const float* e3p = E + (size_t)tok[bt0+3]*Dz;
    float4 a0 = {0,0,0,0}, a1 = {0,0,0,0}, a2 = {0,0,0,0}, a3 = {0,0,0,0};
    for (int d = 0; d < Dz; ++d){
      float4 wv = *(const float4*)(Wx + (size_t)(256 + d)*1024 + u4);
      float e0 = e0p[d], e1 = e1p[d], e2 = e2p[d], e3 = e3p[d];
      a0.x += e0*wv.x; a0.y += e0*wv.y; a0.z += e0*wv.z; a0.w += e0*wv.w;
      a1.x += e1*wv.x; a1.y += e1*wv.y; a1.z += e1*wv.z; a1.w += e1*wv.w;
      a2.x += e2*wv.x; a2.y += e2*wv.y; a2.z += e2*wv.z; a2.w += e2*wv.w;
      a3.x += e3*wv.x; a3.y += e3*wv.y; a3.z += e3*wv.z; a3.w += e3*wv.w;
    }
    *(float4*)(embW + (size_t)(bt0+0)*1024 + u4) = a0;
    *(float4*)(embW + (size_t)(bt0+1)*1024 + u4) = a1;
    *(float4*)(embW + (size_t)(bt0+2)*1024 + u4) = a2;
    *(float4*)(embW + (size_t)(bt0+3)*1024 + u4) = a3;
  }
}

// ---------------- MEGA: XCD-partitioned. blk%8<4 -> recurrence, blk%8>=4 -> logits worker ----
// Recur: rows 2p,2p+1, unit-slice s. NO register arrays: ctx-part via LDS ew (staged once),
// h-part via per-step Wh reads (L2-resident: per-XCD working set Wh 1MB + keys 1MB + Wq
// 0.25MB << 4MB), emb-part via precomputed embW (tiny per-step read). Exchange protocol
// (relaxed agent atomics, no agent fences) unchanged from r5/r8.
__global__ void __launch_bounds__(1024) k_mega(
    const int* __restrict__ tok, const float* __restrict__ h0, const float* __restrict__ c0,
    const float* __restrict__ Wq, const float* __restrict__ bq,
    const float* __restrict__ Vw, const float* __restrict__ bv,
    const float* __restrict__ Wh,
    const float* __restrict__ bl, const float* __restrict__ Wo,
    const float* __restrict__ bo, const float* __restrict__ keys,
    const float* __restrict__ encW, const float* __restrict__ embW,
    float* __restrict__ hs, float* xch, unsigned* flags, unsigned* ctr,
    float* __restrict__ out, float* __restrict__ part)
{
  __shared__ float smem[37512];    // 150,048 B -> 1 block/CU
  const int tid = threadIdx.x;
  const int xcd = blockIdx.x & 7;
  const int widx = blockIdx.x >> 3;   // 0..31 within-XCD index

  if (xcd < 4){
    // ================= RECURRENCE: rows 2p,2p+1 ; unit-slice s =================
    const int p = xcd*4 + (widx >> 3);   // 0..15
    const int s = widx & 7;              // 0..7
    const int lidx = p*8 + s;

    float* ew    = smem;             // [2][128 srow][128 u_local] = 32768
    float* xe    = ew + 32768;       // [2][256]  h only
    float* qv    = xe + 512;         // [2][256]
    float* vl    = qv + 512;         // [256]
    float* selds = vl + 256;         // [2][132]
    float* zp    = selds + 264;      // [2][1024]
    float* qpp   = zp + 2048;        // [4][256]
    float* hnl   = qpp + 1024;       // [2][32]
    float* clds  = hnl + 64;         // [2][32]

    const int u_local = tid & 127;
    const int kc = tid >> 7;
    const int u_gate = ((u_local >> 5) << 8) + (s << 5) + (u_local & 31);

    // --- stage encW slice (2 rows x 128 srow x 128 cols) into LDS ---
    #pragma unroll
    for (int i = 0; i < 32; ++i){
      int gidx = tid + i*1024;
      int r = gidx >> 14, rem = gidx & 16383;
      int srow = rem >> 7, ul = rem & 127;
      int ug = ((ul >> 5) << 8) + (s << 5) + (ul & 31);
      ew[gidx] = encW[(size_t)((2*p + r)*Sz + srow)*1024 + ug];
    }

    const int dq = tid & 255, rq = (tid >> 8) & 1, uh = tid >> 9;

    if (tid < Dz) vl[tid] = Vw[tid];
    if (tid < 64){
      int r = tid >> 5, u = tid & 31;
      hnl[r*32+u] = h0[(2*p+r)*Dz + s*32 + u];
      clds[r*32+u] = c0[(2*p+r)*Dz + s*32 + u];
    }
    __syncthreads();

    // --- initial publish (parity 0, token 1): q-partials from Wq (L2) ---
    {
      const float* wqp = Wq + (size_t)(s*32 + uh*16)*Dz + dq;
      float qp = 0.f;
      #pragma unroll
      for (int uu = 0; uu < 16; ++uu)
        qp = __builtin_fmaf(hnl[rq*32 + uh*16 + uu], wqp[(size_t)uu*Dz], qp);
      qpp[(rq*2 + uh)*256 + dq] = qp;
    }
    __syncthreads();
    {
      float* xn = xch + (size_t)lidx*576;
      if (tid < 512){
        int r = tid >> 8, d = tid & 255;
        st_l3(xn + r*288 + d, qpp[(r*2+0)*256 + d] + qpp[(r*2+1)*256 + d]);
      } else if (tid < 576){
        int r = (tid - 512) >> 5, u = (tid - 512) & 31;
        st_l3(xn + r*288 + 256 + u, hnl[r*32 + u]);
      }
      __syncthreads();   // stores ack'd at L3
      if (tid == 0)
        __hip_atomic_store(flags + lidx, 1u, __ATOMIC_RELAXED, __HIP_MEMORY_SCOPE_AGENT);
    }

    const float bv0 = bv[0];
    const int row2 = tid >> 9, ss = (tid >> 2) & 127, p4 = tid & 3;

    for (int t = 0; t < Tz; ++t){
      // P0: poll the 8 peers of this row-pair
      if (tid < 8){
        const unsigned tgt = (unsigned)(t + 1);
        while (__hip_atomic_load(flags + p*8 + tid, __ATOMIC_RELAXED, __HIP_MEMORY_SCOPE_AGENT) < tgt)
          __builtin_amdgcn_s_sleep(1);
      }
      __syncthreads();
      __builtin_amdgcn_fence(__ATOMIC_ACQUIRE, "workgroup");

      const float* xcp = xch + (size_t)((t & 1)*128 + p*8)*576;
      // P1: assemble q (512 thr) and h (512 thr)
      if (tid < 512){
        int r = tid >> 8, d = tid & 255;
        float q = bq[d];
        #pragma unroll
        for (int s2 = 0; s2 < 8; ++s2) q += ld_l3(xcp + s2*576 + r*288 + d);
        qv[r*256 + d] = q;
      } else {
        int idx = tid - 512, r = idx >> 8, hu = idx & 255;
        xe[r*256 + hu] = ld_l3(xcp + (hu >> 5)*576 + r*288 + 256 + (hu & 31));
      }
      __syncthreads();
      // P2: scores + inline exp
      {
        const int bb_ = 2*p + row2;
        const float* kp = keys + (size_t)(bb_*Sz + ss)*Dz;
        const float* qp_ = qv + row2*256;
        float a = 0.f;
        #pragma unroll
        for (int j = 0; j < 16; ++j){
          const int d0 = j*16 + p4*4;
          float4 kv = *(const float4*)(kp + d0);
          float4 qj = *(const float4*)(qp_ + d0);
          float4 vj = *(const float4*)(vl + d0);
          a += tanhfast(qj.x + kv.x) * vj.x;
          a += tanhfast(qj.y + kv.y) * vj.y;
          a += tanhfast(qj.z + kv.z) * vj.z;
          a += tanhfast(qj.w + kv.w) * vj.w;
        }
        a += __shfl_down(a, 2);
        a += __shfl_down(a, 1);
        if (p4 == 0) selds[row2*132 + ss] = __expf(a + bv0);
      }
      __syncthreads();
      // P3: softmax denom
      if (tid < 128){
        int r = tid >> 6, i = tid & 63;
        float v = selds[r*132 + i] + selds[r*132 + i + 64];
        #pragma unroll
        for (int off = 32; off > 0; off >>= 1) v += __shfl_down(v, off);
        if (i == 0) selds[r*132 + Sz] = 1.0f / v;
      }
      __syncthreads();
      // P4: z partials: h-part from per-step Wh reads (L2-resident, coalesced; one load
      // serves both rows) + ctx-part from LDS ew
      {
        float a1a = 0.f, a1b = 0.f;
        const float* xea = xe + kc*32;
        const float* xeb = xe + 256 + kc*32;
        const float* whp = Wh + (size_t)(kc*32)*1024 + u_gate;
        #pragma unroll
        for (int i = 0; i < 32; ++i){
          float wv = whp[(size_t)i*1024];
          a1a = __builtin_fmaf(xea[i], wv, a1a);
          a1b = __builtin_fmaf(xeb[i], wv, a1b);
        }
        float a2a = 0.f, a2b = 0.f;
        const float* ewa = ew + (kc*16)*128 + u_local;
        const float* ewb = ewa + 16384;
        #pragma unroll
        for (int m = 0; m < 16; ++m){
          a2a = __builtin_fmaf(selds[kc*16 + m],       ewa[m*128], a2a);
          a2b = __builtin_fmaf(selds[132 + kc*16 + m], ewb[m*128], a2b);
        }
        zp[kc*128 + u_local]        = a1a + selds[Sz]*a2a;
        zp[1024 + kc*128 + u_local] = a1b + selds[132 + Sz]*a2b;
      }
      __syncthreads();
      // P5: gate reduce + embW + LSTM + hs publish
      if (tid < 64){
        int r = tid >> 5, u = tid & 31;
        const float* ebw = embW + ((size_t)(2*p + r)*Tz + t)*1024;
        float zi = bl[       s*32 + u] + ebw[        s*32 + u];
        float zf = bl[  Dz + s*32 + u] + ebw[  Dz + s*32 + u];
        float zg = bl[2*Dz + s*32 + u] + ebw[2*Dz + s*32 + u];
        float zo = bl[3*Dz + s*32 + u] + ebw[3*Dz + s*32 + u];
        const float* zpr = zp + r*1024;
        #pragma unroll
        for (int k2 = 0; k2 < 8; ++k2){
          zi += zpr[k2*128 +      u];
          zf += zpr[k2*128 + 32 + u];
          zg += zpr[k2*128 + 64 + u];
          zo += zpr[k2*128 + 96 + u];
        }
        float cn = sigmf(zf)*clds[r*32+u] + sigmf(zi)*tanhfast(zg);
        float hn = sigmf(zo)*tanhfast(cn);
        clds[r*32+u] = cn; hnl[r*32+u] = hn;
        st_l3(hs + (size_t)(t*Bz + 2*p + r)*Dz + s*32 + u, hn);
      }
      __syncthreads();
      // P6a: q-partials for t+1 (Wq from L2)
      {
        const float* wqp = Wq + (size_t)(s*32 + uh*16)*Dz + dq;
        float qp = 0.f;
        #pragma unroll
        for (int uu = 0; uu < 16; ++uu)
          qp = __builtin_fmaf(hnl[rq*32 + uh*16 + uu], wqp[(size_t)uu*Dz], qp);
        qpp[(rq*2 + uh)*256 + dq] = qp;
      }
      __syncthreads();
      // P6b: publish exchange
      {
        float* xn = xch + (size_t)(((t+1) & 1)*128 + lidx)*576;
        if (tid < 512){
          int r = tid >> 8, d = tid & 255;
          st_l3(xn + r*288 + d, qpp[(r*2+0)*256 + d] + qpp[(r*2+1)*256 + d]);
        } else if (tid < 576){
          int r = (tid - 512) >> 5, u = (tid - 512) & 31;
          st_l3(xn + r*288 + 256 + u, hnl[r*32 + u]);
        }
        __syncthreads();   // all stores (incl hs) ack'd at L3
        if (tid == 0)
          __hip_atomic_store(flags + lidx, (unsigned)(t + 2), __ATOMIC_RELAXED, __HIP_MEMORY_SCOPE_AGENT);
      }
    }
  } else {
    // ================= LOGITS WORKER: 256-col slice, 16 row-chunks of 128 =================
    const int wid = (xcd - 4)*32 + widx;   // 0..127
    if (wid >= NWRK) return;               // 3 idle
    const int c0 = wid * 256;
    float* As     = smem;                  // [128][36]
    float* Bs     = As + 128*36;           // [32][264]
    float* rs_row = Bs + 32*264;           // [128]
    float* rq4    = rs_row + 128;          // [128][4]
    float* rinv   = rq4 + 512;             // [128]

    const int ty = tid >> 5, tx = tid & 31;
    float bo8[8];
    #pragma unroll
    for (int jj = 0; jj < 8; ++jj) bo8[jj] = bo[c0 + tx + 32*jj];

    for (int y = 0; y < 16; ++y){
      // wait: all 128 recur blocks past step 4y+3
      const unsigned tgt = (unsigned)(4*y + 5);
      for (;;){
        int ok = 1;
        if (tid < 128)
          ok = (__hip_atomic_load(flags + tid, __ATOMIC_RELAXED, __HIP_MEMORY_SCOPE_AGENT) >= tgt);
        if (__syncthreads_count(ok) == 1024) break;
        __builtin_amdgcn_s_sleep(16);
      }
      __builtin_amdgcn_fence(__ATOMIC_ACQUIRE, "workgroup");

      const int R0 = y * 128;
      float acc[4][8];
      #pragma unroll
      for (int i = 0; i < 4; ++i)
        #pragma unroll
        for (int j = 0; j < 8; ++j) acc[i][j] = 0.f;

      for (int k0 = 0; k0 < Dz; k0 += 32){
        { // stage A [r][k] row-major
          int r = tid >> 3, kq = tid & 7;
          float4 hv = *(const float4*)(hs + (size_t)(R0 + r)*Dz + k0 + kq*4);
          *(float4*)(As + r*36 + kq*4) = hv;
        }
        #pragma unroll
        for (int i = 0; i < 2; ++i){   // stage B [k][c]
          int idx = tid + i*1024;
          int kk = idx >> 6, cq = idx & 63;
          float4 wv = *(const float4*)(Wo + (size_t)(k0 + kk)*Vz + c0 + cq*4);
          *(float4*)(Bs + kk*264 + cq*4) = wv;
        }
        __syncthreads();
        #pragma unroll
        for (int kk = 0; kk < 32; ++kk){
          float ar[4], br[8];
          #pragma unroll
          for (int i = 0; i < 4; ++i) ar[i] = As[(ty*4+i)*36 + kk];
          #pragma unroll
          for (int jj = 0; jj < 8; ++jj) br[jj] = Bs[kk*264 + tx + 32*jj];
          #pragma unroll
          for (int i = 0; i < 4; ++i)
            #pragma unroll
            for (int j = 0; j < 8; ++j)
              acc[i][j] = __builtin_fmaf(ar[i], br[j], acc[i][j]);
        }
        __syncthreads();
      }
      // exp + per-row sums
      #pragma unroll
      for (int i = 0; i < 4; ++i){
        float rp_ = 0.f;
        #pragma unroll
        for (int j = 0; j < 8; ++j){
          acc[i][j] = __expf(acc[i][j] + bo8[j]);
          rp_ += acc[i][j];
        }
        #pragma unroll
        for (int off = 16; off > 0; off >>= 1) rp_ += __shfl_down(rp_, off);
        if (tx == 0) rs_row[ty*4 + i] = rp_;
      }
      __syncthreads();
      if (tid < 128)
        st_l3(part + (size_t)wid*2048 + R0 + tid, rs_row[tid]);
      __syncthreads();
      if (tid == 0){
        __hip_atomic_fetch_add(ctr + y, 1u, __ATOMIC_RELAXED, __HIP_MEMORY_SCOPE_AGENT);
        while (__hip_atomic_load(ctr + y, __ATOMIC_RELAXED, __HIP_MEMORY_SCOPE_AGENT) < (unsigned)NWRK)
          __builtin_amdgcn_s_sleep(8);
      }
      __syncthreads();
      __builtin_amdgcn_fence(__ATOMIC_ACQUIRE, "workgroup");
      // deterministic rowsum over 125 slices (fixed order)
      if (tid < 512){
        int r4 = tid >> 2, q4 = tid & 3;
        int nct = (q4 < 3) ? 32 : 29;
        float sacc = 0.f;
        for (int c2 = 0; c2 < nct; ++c2)
          sacc += ld_l3(part + (size_t)(q4*32 + c2)*2048 + R0 + r4);
        rq4[r4*4 + q4] = sacc;
      }
      __syncthreads();
      if (tid < 128)
        rinv[tid] = 1.0f / (rq4[tid*4] + rq4[tid*4+1] + rq4[tid*4+2] + rq4[tid*4+3]);
      __syncthreads();
      // scale + final write
      #pragma unroll
      for (int i = 0; i < 4; ++i){
        const int R = R0 + ty*4 + i;
        const int orow = (R & 31)*64 + (R >> 5);   // R = t*32+b -> out row b*64+t
        const float iv = rinv[ty*4 + i];
        float* orp = out + (size_t)orow*Vz + c0;
        #pragma unroll
        for (int jj = 0; jj < 8; ++jj)
          orp[tx + 32*jj] = acc[i][jj] * iv;
      }
      __syncthreads();
    }
  }
}

extern "C" void kernel_launch(void* const* d_in, const int* in_sizes, int n_in,
                              void* d_out, int out_size, void* d_ws, size_t ws_size,
                              hipStream_t stream){
  const int*   tok = (const int*)  d_in[0];
  const float* h0  = (const float*)d_in[1];
  const float* c0  = (const float*)d_in[2];
  const float* enc = (const float*)d_in[3];
  const float* E   = (const float*)d_in[4];
  const float* Wq  = (const float*)d_in[5];
  const float* bq  = (const float*)d_in[6];
  const float* Wk  = (const float*)d_in[7];
  const float* bk  = (const float*)d_in[8];
  const float* Vw  = (const float*)d_in[9];
  const float* bv  = (const float*)d_in[10];
  const float* Wx  = (const float*)d_in[11];
  const float* Wh  = (const float*)d_in[12];
  const float* bl  = (const float*)d_in[13];
  const float* Wo  = (const float*)d_in[14];
  const float* bo  = (const float*)d_in[15];
  float* out = (float*)d_out;
  float* ws  = (float*)d_ws;

  float* keys = ws;                        // 1,048,576 f
  float* encW = keys + 1048576;            // 4,194,304 f
  float* embW = encW + 4194304;            // 2,097,152 f (32*64*1024)
  float* hs   = embW + 2097152;            //   524,288 f
  float* xch  = hs   + 524288;             //   147,456 f
  float* part = xch  + 147456;             //   256,000 f  (125 x 2048)
  unsigned* flags = (unsigned*)(part + 256000);  // 128 flags
  unsigned* ctr   = flags + 128;                 // 16 chunk counters

  hipLaunchKernelGGL(k_prep, dim3(1792), dim3(256), 0, stream,
                     enc, Wk, bk, Wx, E, tok, keys, encW, embW, flags);
  hipLaunchKernelGGL(k_mega, dim3(256), dim3(1024), 0, stream,
                     tok, h0, c0, Wq, bq, Vw, bv, Wh, bl, Wo, bo,
                     keys, encW, embW, hs, xch, flags, ctr, out, part);
}

// Round 10
// 2418.876 us; speedup vs baseline: 1.1565x; 1.1565x over previous
//
#include <hip/hip_runtime.h>

#define Bz 32
#define Tz 64
#define Sz 128
#define Dz 256
#define Vz 32000
#define NLG 250    // logits blocks (128-col slice each)

__device__ __forceinline__ float sigmf(float x){ return 1.0f/(1.0f + __expf(-x)); }
__device__ __forceinline__ float tanhfast(float x){ float e = __expf(2.0f*x); return 1.0f - 2.0f/(e+1.0f); }

__device__ __forceinline__ void st_l3(float* p, float v){
  __hip_atomic_store(p, v, __ATOMIC_RELAXED, __HIP_MEMORY_SCOPE_AGENT);
}
__device__ __forceinline__ float ld_l3(const float* p){
  return __hip_atomic_load(p, __ATOMIC_RELAXED, __HIP_MEMORY_SCOPE_AGENT);
}

// ---- K_PREP: keys = enc@Wk+bk ; encW = enc@Wx[0:256] ; embW[b,t] = E[tok]@Wx[256:512] ----
__global__ void __launch_bounds__(256) k_prep(const float* __restrict__ enc,
                                              const float* __restrict__ Wk,
                                              const float* __restrict__ bk,
                                              const float* __restrict__ Wx,
                                              const float* __restrict__ E,
                                              const int* __restrict__ tok,
                                              float* __restrict__ keys,
                                              float* __restrict__ encW,
                                              float* __restrict__ embW,
                                              unsigned* __restrict__ flags,
                                              unsigned* __restrict__ wflags){
  const int blk = blockIdx.x, tid = threadIdx.x;
  if (blk == 0) flags[tid] = 0u;
  if (blk == 1) wflags[tid] = 0u;
  if (blk < 256){
    const int b  = blk >> 3;
    const int s0 = (blk & 7) * 16;
    const float* ebase = enc + (b*Sz + s0)*Dz;
    const int d = tid;
    float acc[16];
    #pragma unroll
    for (int i = 0; i < 16; ++i) acc[i] = 0.f;
    for (int k = 0; k < Dz; k += 4){
      float w0 = Wk[(k+0)*Dz + d], w1 = Wk[(k+1)*Dz + d];
      float w2 = Wk[(k+2)*Dz + d], w3 = Wk[(k+3)*Dz + d];
      #pragma unroll
      for (int si = 0; si < 16; ++si){
        float4 ev = *(const float4*)(ebase + si*Dz + k);
        acc[si] += ev.x*w0 + ev.y*w1 + ev.z*w2 + ev.w*w3;
      }
    }
    const float bkd = bk[d];
    #pragma unroll
    for (int si = 0; si < 16; ++si)
      keys[(b*Sz + s0 + si)*Dz + d] = acc[si] + bkd;
  } else if (blk < 1280){
    const int row0 = (blk - 256) * 4;              // 1024 blocks x 4 rows of enc
    const int u4 = tid * 4;
    float4 a0 = {0,0,0,0}, a1 = {0,0,0,0}, a2 = {0,0,0,0}, a3 = {0,0,0,0};
    for (int d = 0; d < Dz; ++d){
      float4 wv = *(const float4*)(Wx + (size_t)d*1024 + u4);
      float e0 = enc[(size_t)(row0+0)*Dz + d];
      float e1 = enc[(size_t)(row0+1)*Dz + d];
      float e2 = enc[(size_t)(row0+2)*Dz + d];
      float e3 = enc[(size_t)(row0+3)*Dz + d];
      a0.x += e0*wv.x; a0.y += e0*wv.y; a0.z += e0*wv.z; a0.w += e0*wv.w;
      a1.x += e1*wv.x; a1.y += e1*wv.y; a1.z += e1*wv.z; a1.w += e1*wv.w;
      a2.x += e2*wv.x; a2.y += e2*wv.y; a2.z += e2*wv.z; a2.w += e2*wv.w;
      a3.x += e3*wv.x; a3.y += e3*wv.y; a3.z += e3*wv.z; a3.w += e3*wv.w;
    }
    *(float4*)(encW + (size_t)(row0+0)*1024 + u4) = a0;
    *(float4*)(encW + (size_t)(row0+1)*1024 + u4) = a1;
    *(float4*)(encW + (size_t)(row0+2)*1024 + u4) = a2;
    *(float4*)(encW + (size_t)(row0+3)*1024 + u4) = a3;
  } else {
    const int bt0 = (blk - 1280) * 4;              // 512 blocks x 4 (b,t); bt = b*64+t
    const int u4 = tid * 4;
    const float* e0p = E + (size_t)tok[bt0+0]*Dz;
    const float* e1p = E + (size_t)tok[bt0+1]*Dz;
    const float* e2p = E + (size_t)tok[bt0+2]*Dz;
    const float* e3p = E + (size_t)tok[bt0+3]*Dz;
    float4 a0 = {0,0,0,0}, a1 = {0,0,0,0}, a2 = {0,0,0,0}, a3 = {0,0,0,0};
    for (int d = 0; d < Dz; ++d){
      float4 wv = *(const float4*)(Wx + (size_t)(256 + d)*1024 + u4);
      float e0 = e0p[d], e1 = e1p[d], e2 = e2p[d], e3 = e3p[d];
      a0.x += e0*wv.x; a0.y += e0*wv.y; a0.z += e0*wv.z; a0.w += e0*wv.w;
      a1.x += e1*wv.x; a1.y += e1*wv.y; a1.z += e1*wv.z; a1.w += e1*wv.w;
      a2.x += e2*wv.x; a2.y += e2*wv.y; a2.z += e2*wv.z; a2.w += e2*wv.w;
      a3.x += e3*wv.x; a3.y += e3*wv.y; a3.z += e3*wv.z; a3.w += e3*wv.w;
    }
    *(float4*)(embW + (size_t)(bt0+0)*1024 + u4) = a0;
    *(float4*)(embW + (size_t)(bt0+1)*1024 + u4) = a1;
    *(float4*)(embW + (size_t)(bt0+2)*1024 + u4) = a2;
    *(float4*)(embW + (size_t)(bt0+3)*1024 + u4) = a3;
  }
}

// ---------------- K_RECUR: 256 blocks = 32 rows x 8 unit-slices, 1024 thr, 6 phases/step ----
// Exchange per step: {q-partial(256) = h_slice @ Wq-slice, h_slice(32)} via relaxed agent
// atomics (L3), flag protocol proven r5. Gate weights: Wh slice in regs (AGPR-spill ok,
// r5 FETCH=59MB evidence); ctx via LDS ew; emb via precomputed embW (read at P5 only).
__global__ void __launch_bounds__(1024) k_recur(
    const float* __restrict__ h0, const float* __restrict__ c0,
    const float* __restrict__ Wq, const float* __restrict__ bq,
    const float* __restrict__ Vw, const float* __restrict__ bv,
    const float* __restrict__ Wh, const float* __restrict__ bl,
    const float* __restrict__ keys, const float* __restrict__ encW,
    const float* __restrict__ embW,
    float* __restrict__ hs, float* xch, unsigned* flags)
{
  __shared__ float smem[21504];    // 86 KB -> 1 block/CU (256 blocks on 256 CUs)
  float* ew    = smem;             // [128 srow][128 ul] = 16384
  float* qv    = ew + 16384;       // 256
  float* hlds  = qv + 256;         // 256
  float* vl    = hlds + 256;       // 256
  float* selds = vl + 256;         // 128
  float* zpa   = selds + 128;      // [8][128]
  float* zpb   = zpa + 1024;       // [8][128]
  float* hnl   = zpb + 1024;       // 32
  float* clds  = hnl + 32;         // 32

  const int tid = threadIdx.x;
  const int blk = blockIdx.x;
  const int b = ((blk >> 6) << 3) | (blk & 7);   // row (same-XCD heuristic for peers)
  const int s = (blk >> 3) & 7;                  // unit-slice
  const int lidx = b*8 + s;

  const int kc = tid >> 7, ul = tid & 127;
  const int u_gate = ((ul >> 5) << 8) + (s << 5) + (ul & 31);

  // stage ew (ctx weights for this row/slice)
  #pragma unroll
  for (int i = 0; i < 16; ++i){
    int idx = tid + i*1024;
    int srow = idx >> 7, uu = idx & 127;
    int ug = ((uu >> 5) << 8) + (s << 5) + (uu & 31);
    ew[idx] = encW[(size_t)(b*Sz + srow)*1024 + ug];
  }
  // Wh slice in registers (static-indexed; AGPR spill harmless at 1 blk/CU)
  float w[32];
  #pragma unroll
  for (int i = 0; i < 32; ++i) w[i] = Wh[(size_t)(kc*32 + i)*1024 + u_gate];

  if (tid < Dz) vl[tid] = Vw[tid];
  if (tid < 32){
    hnl[tid]  = h0[b*Dz + s*32 + tid];
    clds[tid] = c0[b*Dz + s*32 + tid];
  }
  __syncthreads();

  // initial publish (parity 0, token 1)
  {
    float* xn = xch + (size_t)lidx*288;
    if (tid < 256){
      float qp = 0.f;
      #pragma unroll
      for (int u = 0; u < 32; ++u)
        qp = __builtin_fmaf(hnl[u], Wq[(size_t)(s*32 + u)*Dz + tid], qp);
      st_l3(xn + tid, qp);
    } else if (tid < 288){
      st_l3(xn + tid, hnl[tid - 256]);
    }
    __syncthreads();   // stores ack'd at L3 (vmcnt drained before barrier)
    if (tid == 0)
      __hip_atomic_store(flags + lidx, 1u, __ATOMIC_RELAXED, __HIP_MEMORY_SCOPE_AGENT);
  }

  const float bv0 = bv[0];
  const int ss = tid >> 3, p8 = tid & 7;

  for (int t = 0; t < Tz; ++t){
    // P0: poll the 8 peers of this row
    if (tid < 8){
      const unsigned tgt = (unsigned)(t + 1);
      while (__hip_atomic_load(flags + b*8 + tid, __ATOMIC_RELAXED, __HIP_MEMORY_SCOPE_AGENT) < tgt)
        __builtin_amdgcn_s_sleep(1);
    }
    __syncthreads();
    __builtin_amdgcn_fence(__ATOMIC_ACQUIRE, "workgroup");   // ordering only

    const float* xcp = xch + (size_t)((t & 1)*256 + b*8)*288;
    // P1: assemble q (256 thr) and h (256 thr)
    if (tid < 256){
      float q = bq[tid];
      #pragma unroll
      for (int s2 = 0; s2 < 8; ++s2) q += ld_l3(xcp + s2*288 + tid);
      qv[tid] = q;
    } else if (tid >= 512 && tid < 768){
      const int hu = tid - 512;
      hlds[hu] = ld_l3(xcp + (hu >> 5)*288 + 256 + (hu & 31));
    }
    __syncthreads();
    // P2: scores + inline exp (8 threads per s)
    {
      const float* kp = keys + (size_t)(b*Sz + ss)*Dz;
      float a = 0.f;
      #pragma unroll
      for (int j = 0; j < 8; ++j){
        const int d0 = j*32 + p8*4;
        float4 kv = *(const float4*)(kp + d0);
        float4 qj = *(const float4*)(qv + d0);
        float4 vj = *(const float4*)(vl + d0);
        a += tanhfast(qj.x + kv.x) * vj.x;
        a += tanhfast(qj.y + kv.y) * vj.y;
        a += tanhfast(qj.z + kv.z) * vj.z;
        a += tanhfast(qj.w + kv.w) * vj.w;
      }
      a += __shfl_down(a, 4);
      a += __shfl_down(a, 2);
      a += __shfl_down(a, 1);
      if (p8 == 0) selds[ss] = __expf(a + bv0);
    }
    __syncthreads();
    // P3: z partials (h-part from regs, ctx-part from LDS ew; denom deferred)
    {
      float a1 = 0.f;
      const float* hp = hlds + kc*32;
      #pragma unroll
      for (int i = 0; i < 32; ++i) a1 = __builtin_fmaf(hp[i], w[i], a1);
      float a2 = 0.f;
      const float* ewp = ew + (kc*16)*128 + ul;
      #pragma unroll
      for (int m = 0; m < 16; ++m)
        a2 = __builtin_fmaf(selds[kc*16 + m], ewp[m*128], a2);
      zpa[kc*128 + ul] = a1;
      zpb[kc*128 + ul] = a2;
    }
    __syncthreads();
    // P4: denom (redundant x32, broadcast reads) + gate reduce + LSTM + hs store
    if (tid < 32){
      float dsum = 0.f;
      #pragma unroll
      for (int m = 0; m < 32; ++m){
        float4 sv = *(const float4*)(selds + m*4);
        dsum += sv.x + sv.y + sv.z + sv.w;
      }
      const float inv = 1.0f / dsum;
      const int u = tid;
      const float* ebw = embW + ((size_t)b*Tz + t)*1024;
      float z[4];
      #pragma unroll
      for (int g = 0; g < 4; ++g){
        float za = 0.f, zb = 0.f;
        #pragma unroll
        for (int k2 = 0; k2 < 8; ++k2){
          za += zpa[k2*128 + g*32 + u];
          zb += zpb[k2*128 + g*32 + u];
        }
        z[g] = bl[g*Dz + s*32 + u] + ebw[g*Dz + s*32 + u] + za + inv*zb;
      }
      float cn = sigmf(z[1])*clds[u] + sigmf(z[0])*tanhfast(z[2]);
      float hn = sigmf(z[3])*tanhfast(cn);
      clds[u] = cn; hnl[u] = hn;
      hs[(size_t)(t*Bz + b)*Dz + s*32 + u] = hn;   // plain store (read by next kernel only)
    }
    __syncthreads();
    // P5: publish qp (direct 32-FMA from hnl, Wq from L2) + h
    {
      float* xn = xch + (size_t)(((t+1) & 1)*256 + lidx)*288;
      if (tid < 256){
        float qp = 0.f;
        #pragma unroll
        for (int u = 0; u < 32; ++u)
          qp = __builtin_fmaf(hnl[u], Wq[(size_t)(s*32 + u)*Dz + tid], qp);
        st_l3(xn + tid, qp);
      } else if (tid < 288){
        st_l3(xn + tid, hnl[tid - 256]);
      }
      __syncthreads();   // drain
      if (tid == 0)
        __hip_atomic_store(flags + lidx, (unsigned)(t + 2), __ATOMIC_RELAXED, __HIP_MEMORY_SCOPE_AGENT);
    }
  }
}

// ---------------- K_LOGITS: 250 blocks, 128-col slice; Wo slice in LDS ONCE; fused scale ----
// Per chunk of 128 rows: GEMM (As from L2, Bs from LDS) -> exp -> part publish -> flag-array
// barrier -> deterministic fixed-order rowsum -> scaled single-pass out write.
__global__ void __launch_bounds__(1024) k_logits(
    const float* __restrict__ hs, const float* __restrict__ Wo, const float* __restrict__ bo,
    float* __restrict__ out, float* part, unsigned* wflags)
{
  __shared__ float smem[38784];    // 155 KB -> 1 block/CU; 250 blocks co-resident
  float* Bs     = smem;            // [256][132]
  float* As     = Bs + 256*132;    // [32][132]
  float* rs_row = As + 32*132;     // [128]
  float* rq4    = rs_row + 128;    // [128][4]
  float* rinv   = rq4 + 512;       // [128]

  const int tid = threadIdx.x;
  const int wid = blockIdx.x;
  const int c0  = wid * 128;
  const int ty = tid >> 5, tx = tid & 31;

  // stage Wo slice once: [256 k][128 c]
  #pragma unroll
  for (int i = 0; i < 8; ++i){
    int idx = tid + i*1024;
    int k = idx >> 5, c4 = idx & 31;
    *(float4*)(Bs + k*132 + c4*4) = *(const float4*)(Wo + (size_t)k*Vz + c0 + c4*4);
  }
  const float4 bo4 = *(const float4*)(bo + c0 + tx*4);
  __syncthreads();

  for (int y = 0; y < 16; ++y){
    const int R0 = y * 128;
    float acc[4][4];
    #pragma unroll
    for (int i = 0; i < 4; ++i)
      #pragma unroll
      for (int j = 0; j < 4; ++j) acc[i][j] = 0.f;

    for (int k0 = 0; k0 < Dz; k0 += 32){
      { // stage A^T [k][r]: 128 rows x 32 k (hs L2-shared per XCD)
        int r = tid >> 3, kq = tid & 7;
        float4 hv = *(const float4*)(hs + (size_t)(R0 + r)*Dz + k0 + kq*4);
        As[(kq*4+0)*132 + r] = hv.x; As[(kq*4+1)*132 + r] = hv.y;
        As[(kq*4+2)*132 + r] = hv.z; As[(kq*4+3)*132 + r] = hv.w;
      }
      __syncthreads();
      #pragma unroll
      for (int kk = 0; kk < 32; ++kk){
        float4 av  = *(const float4*)(As + kk*132 + ty*4);
        float4 bb  = *(const float4*)(Bs + (k0+kk)*132 + tx*4);
        float ar[4] = {av.x, av.y, av.z, av.w};
        float br[4] = {bb.x, bb.y, bb.z, bb.w};
        #pragma unroll
        for (int i = 0; i < 4; ++i)
          #pragma unroll
          for (int j = 0; j < 4; ++j)
            acc[i][j] = __builtin_fmaf(ar[i], br[j], acc[i][j]);
      }
      __syncthreads();
    }
    // exp + per-row partial sums (width-32 shuffles)
    #pragma unroll
    for (int i = 0; i < 4; ++i){
      acc[i][0] = __expf(acc[i][0] + bo4.x);
      acc[i][1] = __expf(acc[i][1] + bo4.y);
      acc[i][2] = __expf(acc[i][2] + bo4.z);
      acc[i][3] = __expf(acc[i][3] + bo4.w);
      float rp = acc[i][0] + acc[i][1] + acc[i][2] + acc[i][3];
      #pragma unroll
      for (int off = 16; off > 0; off >>= 1) rp += __shfl_down(rp, off, 32);
      if (tx == 0) rs_row[ty*4 + i] = rp;
    }
    __syncthreads();
    if (tid < 128)
      st_l3(part + (size_t)wid*2048 + R0 + tid, rs_row[tid]);
    __syncthreads();   // part stores ack'd at L3
    if (tid == 0)
      __hip_atomic_store(wflags + wid, (unsigned)(y + 1), __ATOMIC_RELAXED, __HIP_MEMORY_SCOPE_AGENT);
    // flag-array barrier across 250 blocks
    for (;;){
      int ok = 1;
      if (tid < NLG)
        ok = (__hip_atomic_load(wflags + tid, __ATOMIC_RELAXED, __HIP_MEMORY_SCOPE_AGENT) >= (unsigned)(y + 1));
      if (__syncthreads_count(ok) == 1024) break;
      __builtin_amdgcn_s_sleep(8);
    }
    __builtin_amdgcn_fence(__ATOMIC_ACQUIRE, "workgroup");
    // deterministic rowsum over 250 slices: fixed 4-way partition, ascending order
    if (tid < 512){
      int r4 = tid >> 2, q4 = tid & 3;
      int start = (q4 < 2) ? q4*63 : 126 + (q4-2)*62;
      int cnt   = (q4 < 2) ? 63 : 62;
      float sacc = 0.f;
      for (int c = 0; c < cnt; ++c)
        sacc += ld_l3(part + (size_t)(start + c)*2048 + R0 + r4);
      rq4[r4*4 + q4] = sacc;
    }
    __syncthreads();
    if (tid < 128)
      rinv[tid] = 1.0f / (rq4[tid*4] + rq4[tid*4+1] + rq4[tid*4+2] + rq4[tid*4+3]);
    __syncthreads();
    // scaled single-pass write
    #pragma unroll
    for (int i = 0; i < 4; ++i){
      const int R = R0 + ty*4 + i;
      const int orow = (R & 31)*64 + (R >> 5);   // R = t*32+b -> out row b*64+t
      const float iv = rinv[ty*4 + i];
      float4 o;
      o.x = acc[i][0]*iv; o.y = acc[i][1]*iv; o.z = acc[i][2]*iv; o.w = acc[i][3]*iv;
      *(float4*)(out + (size_t)orow*Vz + c0 + tx*4) = o;
    }
    __syncthreads();
  }
}

extern "C" void kernel_launch(void* const* d_in, const int* in_sizes, int n_in,
                              void* d_out, int out_size, void* d_ws, size_t ws_size,
                              hipStream_t stream){
  const int*   tok = (const int*)  d_in[0];
  const float* h0  = (const float*)d_in[1];
  const float* c0  = (const float*)d_in[2];
  const float* enc = (const float*)d_in[3];
  const float* E   = (const float*)d_in[4];
  const float* Wq  = (const float*)d_in[5];
  const float* bq  = (const float*)d_in[6];
  const float* Wk  = (const float*)d_in[7];
  const float* bk  = (const float*)d_in[8];
  const float* Vw  = (const float*)d_in[9];
  const float* bv  = (const float*)d_in[10];
  const float* Wx  = (const float*)d_in[11];
  const float* Wh  = (const float*)d_in[12];
  const float* bl  = (const float*)d_in[13];
  const float* Wo  = (const float*)d_in[14];
  const float* bo  = (const float*)d_in[15];
  float* out = (float*)d_out;
  float* ws  = (float*)d_ws;

  float* keys = ws;                        // 1,048,576 f
  float* encW = keys + 1048576;            // 4,194,304 f
  float* embW = encW + 4194304;            // 2,097,152 f
  float* hs   = embW + 2097152;            //   524,288 f
  float* xch  = hs   + 524288;             //   147,456 f  (2 x 256 x 288)
  float* part = xch  + 147456;             //   512,000 f  (250 x 2048)
  unsigned* flags  = (unsigned*)(part + 512000);  // 256
  unsigned* wflags = flags + 256;                 // 256

  hipLaunchKernelGGL(k_prep, dim3(1792), dim3(256), 0, stream,
                     enc, Wk, bk, Wx, E, tok, keys, encW, embW, flags, wflags);
  hipLaunchKernelGGL(k_recur, dim3(256), dim3(1024), 0, stream,
                     h0, c0, Wq, bq, Vw, bv, Wh, bl, keys, encW, embW,
                     hs, xch, flags);
  hipLaunchKernelGGL(k_logits, dim3(NLG), dim3(1024), 0, stream,
                     hs, Wo, bo, out, part, wflags);
}

// Round 11
// 1835.489 us; speedup vs baseline: 1.5241x; 1.3178x over previous
//
#include <hip/hip_runtime.h>

#define Bz 32
#define Tz 64
#define Sz 128
#define Dz 256
#define Vz 32000
#define NLG 250    // logits blocks (128-col slice each)

__device__ __forceinline__ float sigmf(float x){ return 1.0f/(1.0f + __expf(-x)); }
__device__ __forceinline__ float tanhfast(float x){ float e = __expf(2.0f*x); return 1.0f - 2.0f/(e+1.0f); }

__device__ __forceinline__ void st_l3(float* p, float v){
  __hip_atomic_store(p, v, __ATOMIC_RELAXED, __HIP_MEMORY_SCOPE_AGENT);
}
__device__ __forceinline__ float ld_l3(const float* p){
  return __hip_atomic_load(p, __ATOMIC_RELAXED, __HIP_MEMORY_SCOPE_AGENT);
}

// ---- K_PREP: keys = enc@Wk+bk ; encW = enc@Wx[0:256] ; embW[b,t] = E[tok]@Wx[256:512] ----
__global__ void __launch_bounds__(256) k_prep(const float* __restrict__ enc,
                                              const float* __restrict__ Wk,
                                              const float* __restrict__ bk,
                                              const float* __restrict__ Wx,
                                              const float* __restrict__ E,
                                              const int* __restrict__ tok,
                                              float* __restrict__ keys,
                                              float* __restrict__ encW,
                                              float* __restrict__ embW,
                                              unsigned* __restrict__ flags){
  const int blk = blockIdx.x, tid = threadIdx.x;
  if (blk == 0) flags[tid] = 0u;   // reset barrier flags each launch (graph-replay safe)
  if (blk < 256){
    const int b  = blk >> 3;
    const int s0 = (blk & 7) * 16;
    const float* ebase = enc + (b*Sz + s0)*Dz;
    const int d = tid;
    float acc[16];
    #pragma unroll
    for (int i = 0; i < 16; ++i) acc[i] = 0.f;
    for (int k = 0; k < Dz; k += 4){
      float w0 = Wk[(k+0)*Dz + d], w1 = Wk[(k+1)*Dz + d];
      float w2 = Wk[(k+2)*Dz + d], w3 = Wk[(k+3)*Dz + d];
      #pragma unroll
      for (int si = 0; si < 16; ++si){
        float4 ev = *(const float4*)(ebase + si*Dz + k);
        acc[si] += ev.x*w0 + ev.y*w1 + ev.z*w2 + ev.w*w3;
      }
    }
    const float bkd = bk[d];
    #pragma unroll
    for (int si = 0; si < 16; ++si)
      keys[(b*Sz + s0 + si)*Dz + d] = acc[si] + bkd;
  } else if (blk < 1280){
    const int row0 = (blk - 256) * 4;              // 1024 blocks x 4 rows of enc
    const int u4 = tid * 4;
    float4 a0 = {0,0,0,0}, a1 = {0,0,0,0}, a2 = {0,0,0,0}, a3 = {0,0,0,0};
    for (int d = 0; d < Dz; ++d){
      float4 wv = *(const float4*)(Wx + (size_t)d*1024 + u4);
      float e0 = enc[(size_t)(row0+0)*Dz + d];
      float e1 = enc[(size_t)(row0+1)*Dz + d];
      float e2 = enc[(size_t)(row0+2)*Dz + d];
      float e3 = enc[(size_t)(row0+3)*Dz + d];
      a0.x += e0*wv.x; a0.y += e0*wv.y; a0.z += e0*wv.z; a0.w += e0*wv.w;
      a1.x += e1*wv.x; a1.y += e1*wv.y; a1.z += e1*wv.z; a1.w += e1*wv.w;
      a2.x += e2*wv.x; a2.y += e2*wv.y; a2.z += e2*wv.z; a2.w += e2*wv.w;
      a3.x += e3*wv.x; a3.y += e3*wv.y; a3.z += e3*wv.z; a3.w += e3*wv.w;
    }
    *(float4*)(encW + (size_t)(row0+0)*1024 + u4) = a0;
    *(float4*)(encW + (size_t)(row0+1)*1024 + u4) = a1;
    *(float4*)(encW + (size_t)(row0+2)*1024 + u4) = a2;
    *(float4*)(encW + (size_t)(row0+3)*1024 + u4) = a3;
  } else {
    const int bt0 = (blk - 1280) * 4;              // 512 blocks x 4 (b,t); bt = b*64+t
    const int u4 = tid * 4;
    const float* e0p = E + (size_t)tok[bt0+0]*Dz;
    const float* e1p = E + (size_t)tok[bt0+1]*Dz;
    const float* e2p = E + (size_t)tok[bt0+2]*Dz;
    const float* e3p = E + (size_t)tok[bt0+3]*Dz;
    float4 a0 = {0,0,0,0}, a1 = {0,0,0,0}, a2 = {0,0,0,0}, a3 = {0,0,0,0};
    for (int d = 0; d < Dz; ++d){
      float4 wv = *(const float4*)(Wx + (size_t)(256 + d)*1024 + u4);
      float e0 = e0p[d], e1 = e1p[d], e2 = e2p[d], e3 = e3p[d];
      a0.x += e0*wv.x; a0.y += e0*wv.y; a0.z += e0*wv.z; a0.w += e0*wv.w;
      a1.x += e1*wv.x; a1.y += e1*wv.y; a1.z += e1*wv.z; a1.w += e1*wv.w;
      a2.x += e2*wv.x; a2.y += e2*wv.y; a2.z += e2*wv.z; a2.w += e2*wv.w;
      a3.x += e3*wv.x; a3.y += e3*wv.y; a3.z += e3*wv.z; a3.w += e3*wv.w;
    }
    *(float4*)(embW + (size_t)(bt0+0)*1024 + u4) = a0;
    *(float4*)(embW + (size_t)(bt0+1)*1024 + u4) = a1;
    *(float4*)(embW + (size_t)(bt0+2)*1024 + u4) = a2;
    *(float4*)(embW + (size_t)(bt0+3)*1024 + u4) = a3;
  }
}

// ---------------- K_RECUR: 256 blocks = 32 rows x 8 unit-slices, 1024 thr, 6 phases/step ----
// vs r10: Wq slice staged in LDS (no per-step global Wq loads on critical path);
// embW row prefetched into LDS during P1 by idle threads; bl cached in LDS.
__global__ void __launch_bounds__(1024) k_recur(
    const float* __restrict__ h0, const float* __restrict__ c0,
    const float* __restrict__ Wq, const float* __restrict__ bq,
    const float* __restrict__ Vw, const float* __restrict__ bv,
    const float* __restrict__ Wh, const float* __restrict__ bl,
    const float* __restrict__ keys, const float* __restrict__ encW,
    const float* __restrict__ embW,
    float* __restrict__ hs, float* xch, unsigned* flags)
{
  __shared__ float smem[27776];    // 111,104 B -> 1 block/CU
  float* ew    = smem;             // [128 srow][128 ul] = 16384
  float* wql   = ew + 16384;       // [32 u][256 d] = 8192
  float* qv    = wql + 8192;       // 256
  float* hlds  = qv + 256;         // 256
  float* vl    = hlds + 256;       // 256
  float* selds = vl + 256;         // 128
  float* zpa   = selds + 128;      // [8][128]
  float* zpb   = zpa + 1024;       // [8][128]
  float* hnl   = zpb + 1024;       // 32
  float* clds  = hnl + 32;         // 32
  float* ebw   = clds + 32;        // 128
  float* bll   = ebw + 128;        // 128

  const int tid = threadIdx.x;
  const int blk = blockIdx.x;
  const int b = ((blk >> 6) << 3) | (blk & 7);   // row (same-XCD heuristic for peers)
  const int s = (blk >> 3) & 7;                  // unit-slice
  const int lidx = b*8 + s;

  const int kc = tid >> 7, ul = tid & 127;
  const int u_gate = ((ul >> 5) << 8) + (s << 5) + (ul & 31);

  // stage ew (ctx weights for this row/slice)
  #pragma unroll
  for (int i = 0; i < 16; ++i){
    int idx = tid + i*1024;
    int srow = idx >> 7, uu = idx & 127;
    int ug = ((uu >> 5) << 8) + (s << 5) + (uu & 31);
    ew[idx] = encW[(size_t)(b*Sz + srow)*1024 + ug];
  }
  // stage Wq slice [32 u][256 d] (coalesced)
  #pragma unroll
  for (int i = 0; i < 8; ++i){
    int idx = tid + i*1024;
    wql[idx] = Wq[(size_t)(s*32)*Dz + idx];
  }
  // Wh slice in registers
  float w[32];
  #pragma unroll
  for (int i = 0; i < 32; ++i) w[i] = Wh[(size_t)(kc*32 + i)*1024 + u_gate];

  if (tid < Dz) vl[tid] = Vw[tid];
  if (tid >= 256 && tid < 384) bll[tid-256] = bl[((tid-256) >> 5)*Dz + s*32 + ((tid-256) & 31)];
  if (tid < 32){
    hnl[tid]  = h0[b*Dz + s*32 + tid];
    clds[tid] = c0[b*Dz + s*32 + tid];
  }
  __syncthreads();

  // initial publish (parity 0, token 1) — qp from LDS wql
  {
    float* xn = xch + (size_t)lidx*288;
    if (tid < 256){
      float qp = 0.f;
      #pragma unroll
      for (int u = 0; u < 32; ++u) qp = __builtin_fmaf(hnl[u], wql[u*256 + tid], qp);
      st_l3(xn + tid, qp);
    } else if (tid < 288){
      st_l3(xn + tid, hnl[tid - 256]);
    }
    __syncthreads();   // stores ack'd at L3
    if (tid == 0)
      __hip_atomic_store(flags + lidx, 1u, __ATOMIC_RELAXED, __HIP_MEMORY_SCOPE_AGENT);
  }

  const float bv0 = bv[0];
  const int ss = tid >> 3, p8 = tid & 7;

  for (int t = 0; t < Tz; ++t){
    // P0: poll the 8 peers of this row
    if (tid < 8){
      const unsigned tgt = (unsigned)(t + 1);
      while (__hip_atomic_load(flags + b*8 + tid, __ATOMIC_RELAXED, __HIP_MEMORY_SCOPE_AGENT) < tgt)
        __builtin_amdgcn_s_sleep(1);
    }
    __syncthreads();
    __builtin_amdgcn_fence(__ATOMIC_ACQUIRE, "workgroup");   // ordering only

    const float* xcp = xch + (size_t)((t & 1)*256 + b*8)*288;
    // P1: assemble q (256 thr), h (256 thr), prefetch embW row (128 thr)
    if (tid < 256){
      float q = bq[tid];
      #pragma unroll
      for (int s2 = 0; s2 < 8; ++s2) q += ld_l3(xcp + s2*288 + tid);
      qv[tid] = q;
    } else if (tid >= 512 && tid < 768){
      const int hu = tid - 512;
      hlds[hu] = ld_l3(xcp + (hu >> 5)*288 + 256 + (hu & 31));
    } else if (tid >= 768 && tid < 896){
      const int i = tid - 768;            // g = i>>5, u = i&31
      ebw[i] = embW[((size_t)b*Tz + t)*1024 + (i >> 5)*Dz + s*32 + (i & 31)];
    }
    __syncthreads();
    // P2: scores + inline exp (8 threads per s)
    {
      const float* kp = keys + (size_t)(b*Sz + ss)*Dz;
      float a = 0.f;
      #pragma unroll
      for (int j = 0; j < 8; ++j){
        const int d0 = j*32 + p8*4;
        float4 kv = *(const float4*)(kp + d0);
        float4 qj = *(const float4*)(qv + d0);
        float4 vj = *(const float4*)(vl + d0);
        a += tanhfast(qj.x + kv.x) * vj.x;
        a += tanhfast(qj.y + kv.y) * vj.y;
        a += tanhfast(qj.z + kv.z) * vj.z;
        a += tanhfast(qj.w + kv.w) * vj.w;
      }
      a += __shfl_down(a, 4);
      a += __shfl_down(a, 2);
      a += __shfl_down(a, 1);
      if (p8 == 0) selds[ss] = __expf(a + bv0);
    }
    __syncthreads();
    // P3: z partials (h-part from regs, ctx-part from LDS ew)
    {
      float a1 = 0.f;
      const float* hp = hlds + kc*32;
      #pragma unroll
      for (int i = 0; i < 32; ++i) a1 = __builtin_fmaf(hp[i], w[i], a1);
      float a2 = 0.f;
      const float* ewp = ew + (kc*16)*128 + ul;
      #pragma unroll
      for (int m = 0; m < 16; ++m)
        a2 = __builtin_fmaf(selds[kc*16 + m], ewp[m*128], a2);
      zpa[kc*128 + ul] = a1;
      zpb[kc*128 + ul] = a2;
    }
    __syncthreads();
    // P4: denom (redundant x32) + gate reduce + LSTM + hs store (all LDS operands)
    if (tid < 32){
      float dsum = 0.f;
      #pragma unroll
      for (int m = 0; m < 32; ++m){
        float4 sv = *(const float4*)(selds + m*4);
        dsum += sv.x + sv.y + sv.z + sv.w;
      }
      const float inv = 1.0f / dsum;
      const int u = tid;
      float z[4];
      #pragma unroll
      for (int g = 0; g < 4; ++g){
        float za = 0.f, zb = 0.f;
        #pragma unroll
        for (int k2 = 0; k2 < 8; ++k2){
          za += zpa[k2*128 + g*32 + u];
          zb += zpb[k2*128 + g*32 + u];
        }
        z[g] = bll[g*32 + u] + ebw[g*32 + u] + za + inv*zb;
      }
      float cn = sigmf(z[1])*clds[u] + sigmf(z[0])*tanhfast(z[2]);
      float hn = sigmf(z[3])*tanhfast(cn);
      clds[u] = cn; hnl[u] = hn;
      hs[(size_t)(t*Bz + b)*Dz + s*32 + u] = hn;
    }
    __syncthreads();
    // P5: publish qp (pure LDS FMA from wql) + h
    {
      float* xn = xch + (size_t)(((t+1) & 1)*256 + lidx)*288;
      if (tid < 256){
        float qp = 0.f;
        #pragma unroll
        for (int u = 0; u < 32; ++u) qp = __builtin_fmaf(hnl[u], wql[u*256 + tid], qp);
        st_l3(xn + tid, qp);
      } else if (tid < 288){
        st_l3(xn + tid, hnl[tid - 256]);
      }
      __syncthreads();   // drain
      if (tid == 0)
        __hip_atomic_store(flags + lidx, (unsigned)(t + 2), __ATOMIC_RELAXED, __HIP_MEMORY_SCOPE_AGENT);
    }
  }
}

// ---------------- K_LOGITS: 250 persistent blocks, 128-col slice; Wo in LDS ONCE; ---------
// NO inter-block barriers: writes UNSCALED exp to out + per-chunk row partials to part.
__global__ void __launch_bounds__(1024) k_logits(
    const float* __restrict__ hs, const float* __restrict__ Wo, const float* __restrict__ bo,
    float* __restrict__ out, float* __restrict__ part)
{
  __shared__ float smem[38144];    // 152,576 B -> 1 block/CU
  float* Bs     = smem;            // [256][132]
  float* As     = Bs + 256*132;    // [32][132]
  float* rs_row = As + 32*132;     // [128]

  const int tid = threadIdx.x;
  const int wid = blockIdx.x;
  const int c0  = wid * 128;
  const int ty = tid >> 5, tx = tid & 31;

  // stage Wo slice once: [256 k][128 c]  (Wo read exactly once from HBM, total 32 MB)
  #pragma unroll
  for (int i = 0; i < 8; ++i){
    int idx = tid + i*1024;
    int k = idx >> 5, c4 = idx & 31;
    *(float4*)(Bs + k*132 + c4*4) = *(const float4*)(Wo + (size_t)k*Vz + c0 + c4*4);
  }
  const float4 bo4 = *(const float4*)(bo + c0 + tx*4);
  __syncthreads();

  for (int y = 0; y < 16; ++y){
    const int R0 = y * 128;
    float acc[4][4];
    #pragma unroll
    for (int i = 0; i < 4; ++i)
      #pragma unroll
      for (int j = 0; j < 4; ++j) acc[i][j] = 0.f;

    for (int k0 = 0; k0 < Dz; k0 += 32){
      { // stage A^T [k][r]: 128 rows x 32 k
        int r = tid >> 3, kq = tid & 7;
        float4 hv = *(const float4*)(hs + (size_t)(R0 + r)*Dz + k0 + kq*4);
        As[(kq*4+0)*132 + r] = hv.x; As[(kq*4+1)*132 + r] = hv.y;
        As[(kq*4+2)*132 + r] = hv.z; As[(kq*4+3)*132 + r] = hv.w;
      }
      __syncthreads();
      #pragma unroll
      for (int kk = 0; kk < 32; ++kk){
        float4 av  = *(const float4*)(As + kk*132 + ty*4);
        float4 bb  = *(const float4*)(Bs + (k0+kk)*132 + tx*4);
        float ar[4] = {av.x, av.y, av.z, av.w};
        float br[4] = {bb.x, bb.y, bb.z, bb.w};
        #pragma unroll
        for (int i = 0; i < 4; ++i)
          #pragma unroll
          for (int j = 0; j < 4; ++j)
            acc[i][j] = __builtin_fmaf(ar[i], br[j], acc[i][j]);
      }
      __syncthreads();
    }
    // exp + unscaled store + per-row partial sums
    #pragma unroll
    for (int i = 0; i < 4; ++i){
      const int R = R0 + ty*4 + i;
      const int orow = (R & 31)*64 + (R >> 5);   // R = t*32+b -> out row b*64+t
      float4 o;
      o.x = __expf(acc[i][0] + bo4.x);
      o.y = __expf(acc[i][1] + bo4.y);
      o.z = __expf(acc[i][2] + bo4.z);
      o.w = __expf(acc[i][3] + bo4.w);
      *(float4*)(out + (size_t)orow*Vz + c0 + tx*4) = o;
      float rp = o.x + o.y + o.z + o.w;
      #pragma unroll
      for (int off = 16; off > 0; off >>= 1) rp += __shfl_down(rp, off, 32);
      if (tx == 0) rs_row[ty*4 + i] = rp;
    }
    __syncthreads();
    if (tid < 128)
      part[(size_t)wid*2048 + R0 + tid] = rs_row[tid];
    __syncthreads();
  }
}

// ---------------- K_SCALE: deterministic rowsum over 250 partials + in-place scale ----------
__global__ void __launch_bounds__(256) k_scale(float* __restrict__ out, const float* __restrict__ part){
  const int row = blockIdx.x;              // out-row = b*64 + t
  const int b = row >> 6, tt = row & 63;
  const int R = tt*Bz + b;
  const int tid = threadIdx.x;
  __shared__ float ssum[4];
  float v = (tid < NLG) ? part[(size_t)tid*2048 + R] : 0.f;
  #pragma unroll
  for (int off = 32; off > 0; off >>= 1) v += __shfl_down(v, off);
  if ((tid & 63) == 0) ssum[tid >> 6] = v;
  __syncthreads();
  const float inv = 1.0f / (ssum[0] + ssum[1] + ssum[2] + ssum[3]);
  float4* rp = (float4*)(out + (size_t)row*Vz);
  for (int j4 = tid; j4 < Vz/4; j4 += 256){
    float4 x = rp[j4];
    x.x *= inv; x.y *= inv; x.z *= inv; x.w *= inv;
    rp[j4] = x;
  }
}

extern "C" void kernel_launch(void* const* d_in, const int* in_sizes, int n_in,
                              void* d_out, int out_size, void* d_ws, size_t ws_size,
                              hipStream_t stream){
  const int*   tok = (const int*)  d_in[0];
  const float* h0  = (const float*)d_in[1];
  const float* c0  = (const float*)d_in[2];
  const float* enc = (const float*)d_in[3];
  const float* E   = (const float*)d_in[4];
  const float* Wq  = (const float*)d_in[5];
  const float* bq  = (const float*)d_in[6];
  const float* Wk  = (const float*)d_in[7];
  const float* bk  = (const float*)d_in[8];
  const float* Vw  = (const float*)d_in[9];
  const float* bv  = (const float*)d_in[10];
  const float* Wx  = (const float*)d_in[11];
  const float* Wh  = (const float*)d_in[12];
  const float* bl  = (const float*)d_in[13];
  const float* Wo  = (const float*)d_in[14];
  const float* bo  = (const float*)d_in[15];
  float* out = (float*)d_out;
  float* ws  = (float*)d_ws;

  float* keys = ws;                        // 1,048,576 f
  float* encW = keys + 1048576;            // 4,194,304 f
  float* embW = encW + 4194304;            // 2,097,152 f
  float* hs   = embW + 2097152;            //   524,288 f
  float* xch  = hs   + 524288;             //   147,456 f  (2 x 256 x 288)
  float* part = xch  + 147456;             //   512,000 f  (250 x 2048)
  unsigned* flags = (unsigned*)(part + 512000);  // 256

  hipLaunchKernelGGL(k_prep, dim3(1792), dim3(256), 0, stream,
                     enc, Wk, bk, Wx, E, tok, keys, encW, embW, flags);
  hipLaunchKernelGGL(k_recur, dim3(256), dim3(1024), 0, stream,
                     h0, c0, Wq, bq, Vw, bv, Wh, bl, keys, encW, embW,
                     hs, xch, flags);
  hipLaunchKernelGGL(k_logits, dim3(NLG), dim3(1024), 0, stream,
                     hs, Wo, bo, out, part);
  hipLaunchKernelGGL(k_scale, dim3(2048), dim3(256), 0, stream, out, part);
}

// Round 12
// 1653.369 us; speedup vs baseline: 1.6920x; 1.1102x over previous
//
#include <hip/hip_runtime.h>

#define Bz 32
#define Tz 64
#define Sz 128
#define Dz 256
#define Vz 32000
#define NLG 250    // logits blocks (128-col slice each)

__device__ __forceinline__ float sigmf(float x){ return 1.0f/(1.0f + __expf(-x)); }
__device__ __forceinline__ float tanhfast(float x){ float e = __expf(2.0f*x); return 1.0f - 2.0f/(e+1.0f); }

__device__ __forceinline__ void st_l3(float* p, float v){
  __hip_atomic_store(p, v, __ATOMIC_RELAXED, __HIP_MEMORY_SCOPE_AGENT);
}
__device__ __forceinline__ float ld_l3(const float* p){
  return __hip_atomic_load(p, __ATOMIC_RELAXED, __HIP_MEMORY_SCOPE_AGENT);
}

// ---- K_PREP: keys = enc@Wk+bk ; encW = enc@Wx[0:256] ; embW[b,t] = E[tok]@Wx[256:512] ----
__global__ void __launch_bounds__(256) k_prep(const float* __restrict__ enc,
                                              const float* __restrict__ Wk,
                                              const float* __restrict__ bk,
                                              const float* __restrict__ Wx,
                                              const float* __restrict__ E,
                                              const int* __restrict__ tok,
                                              float* __restrict__ keys,
                                              float* __restrict__ encW,
                                              float* __restrict__ embW,
                                              unsigned* __restrict__ flags){
  const int blk = blockIdx.x, tid = threadIdx.x;
  if (blk == 0) flags[tid] = 0u;   // reset flags (kernel-end flush publishes to L3)
  if (blk < 256){
    const int b  = blk >> 3;
    const int s0 = (blk & 7) * 16;
    const float* ebase = enc + (b*Sz + s0)*Dz;
    const int d = tid;
    float acc[16];
    #pragma unroll
    for (int i = 0; i < 16; ++i) acc[i] = 0.f;
    for (int k = 0; k < Dz; k += 4){
      float w0 = Wk[(k+0)*Dz + d], w1 = Wk[(k+1)*Dz + d];
      float w2 = Wk[(k+2)*Dz + d], w3 = Wk[(k+3)*Dz + d];
      #pragma unroll
      for (int si = 0; si < 16; ++si){
        float4 ev = *(const float4*)(ebase + si*Dz + k);
        acc[si] += ev.x*w0 + ev.y*w1 + ev.z*w2 + ev.w*w3;
      }
    }
    const float bkd = bk[d];
    #pragma unroll
    for (int si = 0; si < 16; ++si)
      keys[(b*Sz + s0 + si)*Dz + d] = acc[si] + bkd;
  } else if (blk < 1280){
    const int row0 = (blk - 256) * 4;
    const int u4 = tid * 4;
    float4 a0 = {0,0,0,0}, a1 = {0,0,0,0}, a2 = {0,0,0,0}, a3 = {0,0,0,0};
    for (int d = 0; d < Dz; ++d){
      float4 wv = *(const float4*)(Wx + (size_t)d*1024 + u4);
      float e0 = enc[(size_t)(row0+0)*Dz + d];
      float e1 = enc[(size_t)(row0+1)*Dz + d];
      float e2 = enc[(size_t)(row0+2)*Dz + d];
      float e3 = enc[(size_t)(row0+3)*Dz + d];
      a0.x += e0*wv.x; a0.y += e0*wv.y; a0.z += e0*wv.z; a0.w += e0*wv.w;
      a1.x += e1*wv.x; a1.y += e1*wv.y; a1.z += e1*wv.z; a1.w += e1*wv.w;
      a2.x += e2*wv.x; a2.y += e2*wv.y; a2.z += e2*wv.z; a2.w += e2*wv.w;
      a3.x += e3*wv.x; a3.y += e3*wv.y; a3.z += e3*wv.z; a3.w += e3*wv.w;
    }
    *(float4*)(encW + (size_t)(row0+0)*1024 + u4) = a0;
    *(float4*)(encW + (size_t)(row0+1)*1024 + u4) = a1;
    *(float4*)(encW + (size_t)(row0+2)*1024 + u4) = a2;
    *(float4*)(encW + (size_t)(row0+3)*1024 + u4) = a3;
  } else {
    const int bt0 = (blk - 1280) * 4;
    const int u4 = tid * 4;
    const float* e0p = E + (size_t)tok[bt0+0]*Dz;
    const float* e1p = E + (size_t)tok[bt0+1]*Dz;
    const float* e2p = E + (size_t)tok[bt0+2]*Dz;
    const float* e3p = E + (size_t)tok[bt0+3]*Dz;
    float4 a0 = {0,0,0,0}, a1 = {0,0,0,0}, a2 = {0,0,0,0}, a3 = {0,0,0,0};
    for (int d = 0; d < Dz; ++d){
      float4 wv = *(const float4*)(Wx + (size_t)(256 + d)*1024 + u4);
      float e0 = e0p[d], e1 = e1p[d], e2 = e2p[d], e3 = e3p[d];
      a0.x += e0*wv.x; a0.y += e0*wv.y; a0.z += e0*wv.z; a0.w += e0*wv.w;
      a1.x += e1*wv.x; a1.y += e1*wv.y; a1.z += e1*wv.z; a1.w += e1*wv.w;
      a2.x += e2*wv.x; a2.y += e2*wv.y; a2.z += e2*wv.z; a2.w += e2*wv.w;
      a3.x += e3*wv.x; a3.y += e3*wv.y; a3.z += e3*wv.z; a3.w += e3*wv.w;
    }
    *(float4*)(embW + (size_t)(bt0+0)*1024 + u4) = a0;
    *(float4*)(embW + (size_t)(bt0+1)*1024 + u4) = a1;
    *(float4*)(embW + (size_t)(bt0+2)*1024 + u4) = a2;
    *(float4*)(embW + (size_t)(bt0+3)*1024 + u4) = a3;
  }
}

// ---------------- K_RECUR: 256 blocks = 32 rows x 8 unit-slices; 3 barriers/step ----------
// A: per-WAVE poll + exchange reads (no poll->load barrier). B: scores+zpa. C: zb+denom.
// D+E on wave0 only, no barrier: LSTM -> qp -> 288 L3 stores -> wave-local vmcnt(0) -> flag.
// Buffer safety: any writer of step t+1 sits behind a poll of this block's own flag, which
// is set only after D/E of step t completed. ebw double-buffered by parity.
__global__ void __launch_bounds__(1024) k_recur(
    const float* __restrict__ h0, const float* __restrict__ c0,
    const float* __restrict__ Wq, const float* __restrict__ bq,
    const float* __restrict__ Vw, const float* __restrict__ bv,
    const float* __restrict__ Wh, const float* __restrict__ bl,
    const float* __restrict__ keys, const float* __restrict__ encW,
    const float* __restrict__ embW,
    float* __restrict__ hs, float* xch, unsigned* flags)
{
  __shared__ float smem[27960];    // 111,840 B -> 1 block/CU
  float* ew    = smem;             // [128 srow][128 ul] = 16384
  float* wql   = ew + 16384;       // [32 u][256 d] = 8192
  float* qv    = wql + 8192;       // 256
  float* hlds  = qv + 256;         // 256
  float* vl    = hlds + 256;       // 256
  float* selds = vl + 256;         // 132 (128 scores + inv at [128])
  float* zpa   = selds + 132;      // [8][128]
  float* zpb   = zpa + 1024;       // [8][128]
  float* hnl   = zpb + 1024;       // 32
  float* clds  = hnl + 32;         // 32
  float* ebw   = clds + 32;        // [2][128] parity-double-buffered
  float* bll   = ebw + 256;        // 128

  const int tid = threadIdx.x;
  const int blk = blockIdx.x;
  const int b = ((blk >> 6) << 3) | (blk & 7);   // row
  const int s = (blk >> 3) & 7;                  // unit-slice
  const int lidx = b*8 + s;
  const int wave = tid >> 6, lane = tid & 63;

  const int kc = tid >> 7, ul = tid & 127;
  const int u_gate = ((ul >> 5) << 8) + (s << 5) + (ul & 31);

  // ---- one-time staging ----
  #pragma unroll
  for (int i = 0; i < 16; ++i){
    int idx = tid + i*1024;
    int srow = idx >> 7, uu = idx & 127;
    int ug = ((uu >> 5) << 8) + (s << 5) + (uu & 31);
    ew[idx] = encW[(size_t)(b*Sz + srow)*1024 + ug];
  }
  #pragma unroll
  for (int i = 0; i < 8; ++i){
    int idx = tid + i*1024;
    wql[idx] = Wq[(size_t)(s*32)*Dz + idx];
  }
  float w[32];   // Wh slice (spills to AGPR at worst — on-chip)
  #pragma unroll
  for (int i = 0; i < 32; ++i) w[i] = Wh[(size_t)(kc*32 + i)*1024 + u_gate];

  if (tid < Dz) vl[tid] = Vw[tid];
  if (tid >= 256 && tid < 384) bll[tid-256] = bl[((tid-256) >> 5)*Dz + s*32 + ((tid-256) & 31)];
  if (tid < 32){
    hnl[tid]  = h0[b*Dz + s*32 + tid];
    clds[tid] = c0[b*Dz + s*32 + tid];
  }
  __syncthreads();

  // ---- initial publish (wave0 only): publish(0) parity0, token 1 ----
  if (wave == 0){
    float* xn = xch + (size_t)lidx*288;
    float4 qp = {0.f, 0.f, 0.f, 0.f};
    #pragma unroll
    for (int u = 0; u < 32; ++u){
      float hu_ = hnl[u];
      float4 wv = *(const float4*)(wql + u*256 + lane*4);
      qp.x = __builtin_fmaf(hu_, wv.x, qp.x);
      qp.y = __builtin_fmaf(hu_, wv.y, qp.y);
      qp.z = __builtin_fmaf(hu_, wv.z, qp.z);
      qp.w = __builtin_fmaf(hu_, wv.w, qp.w);
    }
    st_l3(xn + lane*4 + 0, qp.x);
    st_l3(xn + lane*4 + 1, qp.y);
    st_l3(xn + lane*4 + 2, qp.z);
    st_l3(xn + lane*4 + 3, qp.w);
    if (lane < 32) st_l3(xn + 256 + lane, hnl[lane]);
    asm volatile("s_waitcnt vmcnt(0)" ::: "memory");
    if (lane == 0)
      __hip_atomic_store(flags + lidx, 1u, __ATOMIC_RELAXED, __HIP_MEMORY_SCOPE_AGENT);
  }

  const float bv0 = bv[0];
  const int ss = tid >> 3, p8 = tid & 7;

  for (int t = 0; t < Tz; ++t){
    // ---- A: per-wave poll + exchange reads ----
    if (wave >= 2 && wave <= 9){
      if (lane < 8){
        const unsigned tgt = (unsigned)(t + 1);
        while (__hip_atomic_load(flags + b*8 + lane, __ATOMIC_RELAXED, __HIP_MEMORY_SCOPE_AGENT) < tgt)
          __builtin_amdgcn_s_sleep(1);
      }
      __builtin_amdgcn_fence(__ATOMIC_ACQUIRE, "workgroup");   // compiler ordering; no cache inv
      const float* xcp = xch + (size_t)((t & 1)*256 + b*8)*288;
      if (wave < 6){
        const int d = tid - 128;           // 0..255
        float q = bq[d];
        #pragma unroll
        for (int s2 = 0; s2 < 8; ++s2) q += ld_l3(xcp + s2*288 + d);
        qv[d] = q;
      } else {
        const int hu = tid - 384;          // 0..255
        hlds[hu] = ld_l3(xcp + (hu >> 5)*288 + 256 + (hu & 31));
      }
    } else if (wave == 1){
      const float* ep = embW + ((size_t)b*Tz + t)*1024;
      #pragma unroll
      for (int rr = 0; rr < 2; ++rr){
        int i = lane + rr*64;
        ebw[(t & 1)*128 + i] = ep[(i >> 5)*Dz + s*32 + (i & 31)];
      }
    }
    __syncthreads();   // A-bar

    // ---- B: scores+exp AND zpa (independent tasks, same phase) ----
    {
      const float* kp = keys + (size_t)(b*Sz + ss)*Dz;
      float a = 0.f;
      #pragma unroll
      for (int j = 0; j < 8; ++j){
        const int d0 = j*32 + p8*4;
        float4 kv = *(const float4*)(kp + d0);
        float4 qj = *(const float4*)(qv + d0);
        float4 vj = *(const float4*)(vl + d0);
        a += tanhfast(qj.x + kv.x) * vj.x;
        a += tanhfast(qj.y + kv.y) * vj.y;
        a += tanhfast(qj.z + kv.z) * vj.z;
        a += tanhfast(qj.w + kv.w) * vj.w;
      }
      a += __shfl_down(a, 4);
      a += __shfl_down(a, 2);
      a += __shfl_down(a, 1);
      if (p8 == 0) selds[ss] = __expf(a + bv0);

      float a1 = 0.f;
      const float* hp = hlds + kc*32;
      #pragma unroll
      for (int i = 0; i < 32; ++i) a1 = __builtin_fmaf(hp[i], w[i], a1);
      zpa[kc*128 + ul] = a1;
    }
    __syncthreads();   // B-bar

    // ---- C: zb AND denom (wave15) ----
    {
      float a2 = 0.f;
      const float* ewp = ew + (kc*16)*128 + ul;
      #pragma unroll
      for (int m = 0; m < 16; ++m)
        a2 = __builtin_fmaf(selds[kc*16 + m], ewp[m*128], a2);
      zpb[kc*128 + ul] = a2;
      if (wave == 15){
        const int l = lane;
        float v = selds[l] + selds[l + 64];
        #pragma unroll
        for (int off = 32; off > 0; off >>= 1) v += __shfl_down(v, off);
        if (l == 0) selds[Sz] = 1.0f / v;
      }
    }
    __syncthreads();   // C-bar

    // ---- D+E: wave0 only, no barrier (others proceed to next poll) ----
    if (wave == 0){
      if (lane < 32){
        const int u = lane;
        const float inv = selds[Sz];
        float z[4];
        #pragma unroll
        for (int g = 0; g < 4; ++g){
          float za = 0.f, zb = 0.f;
          #pragma unroll
          for (int k2 = 0; k2 < 8; ++k2){
            za += zpa[k2*128 + g*32 + u];
            zb += zpb[k2*128 + g*32 + u];
          }
          z[g] = bll[g*32 + u] + ebw[(t & 1)*128 + g*32 + u] + za + inv*zb;
        }
        float cn = sigmf(z[1])*clds[u] + sigmf(z[0])*tanhfast(z[2]);
        float hn = sigmf(z[3])*tanhfast(cn);
        clds[u] = cn; hnl[u] = hn;
        hs[(size_t)(t*Bz + b)*Dz + s*32 + u] = hn;   // plain store, consumed next kernel
      }
      // E: qp publish (reads hnl via LDS; wave-internal lgkmcnt ordering by compiler)
      float* xn = xch + (size_t)(((t+1) & 1)*256 + lidx)*288;
      float4 qp = {0.f, 0.f, 0.f, 0.f};
      #pragma unroll
      for (int u = 0; u < 32; ++u){
        float hu_ = hnl[u];
        float4 wv = *(const float4*)(wql + u*256 + lane*4);
        qp.x = __builtin_fmaf(hu_, wv.x, qp.x);
        qp.y = __builtin_fmaf(hu_, wv.y, qp.y);
        qp.z = __builtin_fmaf(hu_, wv.z, qp.z);
        qp.w = __builtin_fmaf(hu_, wv.w, qp.w);
      }
      st_l3(xn + lane*4 + 0, qp.x);
      st_l3(xn + lane*4 + 1, qp.y);
      st_l3(xn + lane*4 + 2, qp.z);
      st_l3(xn + lane*4 + 3, qp.w);
      if (lane < 32) st_l3(xn + 256 + lane, hnl[lane]);
      asm volatile("s_waitcnt vmcnt(0)" ::: "memory");   // wave-local drain (incl. hs)
      if (lane == 0)
        __hip_atomic_store(flags + lidx, (unsigned)(t + 2), __ATOMIC_RELAXED, __HIP_MEMORY_SCOPE_AGENT);
    }
  }
}

// ---------------- K_LOGITS: 250 persistent blocks, 128-col slice; Wo in LDS ONCE ---------
__global__ void __launch_bounds__(1024) k_logits(
    const float* __restrict__ hs, const float* __restrict__ Wo, const float* __restrict__ bo,
    float* __restrict__ out, float* __restrict__ part)
{
  __shared__ float smem[38144];    // 152,576 B -> 1 block/CU
  float* Bs     = smem;            // [256][132]
  float* As     = Bs + 256*132;    // [32][132]
  float* rs_row = As + 32*132;     // [128]

  const int tid = threadIdx.x;
  const int wid = blockIdx.x;
  const int c0  = wid * 128;
  const int ty = tid >> 5, tx = tid & 31;

  #pragma unroll
  for (int i = 0; i < 8; ++i){
    int idx = tid + i*1024;
    int k = idx >> 5, c4 = idx & 31;
    *(float4*)(Bs + k*132 + c4*4) = *(const float4*)(Wo + (size_t)k*Vz + c0 + c4*4);
  }
  const float4 bo4 = *(const float4*)(bo + c0 + tx*4);
  __syncthreads();

  for (int y = 0; y < 16; ++y){
    const int R0 = y * 128;
    float acc[4][4];
    #pragma unroll
    for (int i = 0; i < 4; ++i)
      #pragma unroll
      for (int j = 0; j < 4; ++j) acc[i][j] = 0.f;

    for (int k0 = 0; k0 < Dz; k0 += 32){
      {
        int r = tid >> 3, kq = tid & 7;
        float4 hv = *(const float4*)(hs + (size_t)(R0 + r)*Dz + k0 + kq*4);
        As[(kq*4+0)*132 + r] = hv.x; As[(kq*4+1)*132 + r] = hv.y;
        As[(kq*4+2)*132 + r] = hv.z; As[(kq*4+3)*132 + r] = hv.w;
      }
      __syncthreads();
      #pragma unroll
      for (int kk = 0; kk < 32; ++kk){
        float4 av  = *(const float4*)(As + kk*132 + ty*4);
        float4 bb  = *(const float4*)(Bs + (k0+kk)*132 + tx*4);
        float ar[4] = {av.x, av.y, av.z, av.w};
        float br[4] = {bb.x, bb.y, bb.z, bb.w};
        #pragma unroll
        for (int i = 0; i < 4; ++i)
          #pragma unroll
          for (int j = 0; j < 4; ++j)
            acc[i][j] = __builtin_fmaf(ar[i], br[j], acc[i][j]);
      }
      __syncthreads();
    }
    #pragma unroll
    for (int i = 0; i < 4; ++i){
      const int R = R0 + ty*4 + i;
      const int orow = (R & 31)*64 + (R >> 5);
      float4 o;
      o.x = __expf(acc[i][0] + bo4.x);
      o.y = __expf(acc[i][1] + bo4.y);
      o.z = __expf(acc[i][2] + bo4.z);
      o.w = __expf(acc[i][3] + bo4.w);
      *(float4*)(out + (size_t)orow*Vz + c0 + tx*4) = o;
      float rp = o.x + o.y + o.z + o.w;
      #pragma unroll
      for (int off = 16; off > 0; off >>= 1) rp += __shfl_down(rp, off, 32);
      if (tx == 0) rs_row[ty*4 + i] = rp;
    }
    __syncthreads();
    if (tid < 128)
      part[(size_t)wid*2048 + R0 + tid] = rs_row[tid];
    __syncthreads();
  }
}

// ---------------- K_SCALE: deterministic rowsum over 250 partials + in-place scale ----------
__global__ void __launch_bounds__(256) k_scale(float* __restrict__ out, const float* __restrict__ part){
  const int row = blockIdx.x;
  const int b = row >> 6, tt = row & 63;
  const int R = tt*Bz + b;
  const int tid = threadIdx.x;
  __shared__ float ssum[4];
  float v = (tid < NLG) ? part[(size_t)tid*2048 + R] : 0.f;
  #pragma unroll
  for (int off = 32; off > 0; off >>= 1) v += __shfl_down(v, off);
  if ((tid & 63) == 0) ssum[tid >> 6] = v;
  __syncthreads();
  const float inv = 1.0f / (ssum[0] + ssum[1] + ssum[2] + ssum[3]);
  float4* rp = (float4*)(out + (size_t)row*Vz);
  for (int j4 = tid; j4 < Vz/4; j4 += 256){
    float4 x = rp[j4];
    x.x *= inv; x.y *= inv; x.z *= inv; x.w *= inv;
    rp[j4] = x;
  }
}

extern "C" void kernel_launch(void* const* d_in, const int* in_sizes, int n_in,
                              void* d_out, int out_size, void* d_ws, size_t ws_size,
                              hipStream_t stream){
  const int*   tok = (const int*)  d_in[0];
  const float* h0  = (const float*)d_in[1];
  const float* c0  = (const float*)d_in[2];
  const float* enc = (const float*)d_in[3];
  const float* E   = (const float*)d_in[4];
  const float* Wq  = (const float*)d_in[5];
  const float* bq  = (const float*)d_in[6];
  const float* Wk  = (const float*)d_in[7];
  const float* bk  = (const float*)d_in[8];
  const float* Vw  = (const float*)d_in[9];
  const float* bv  = (const float*)d_in[10];
  const float* Wx  = (const float*)d_in[11];
  const float* Wh  = (const float*)d_in[12];
  const float* bl  = (const float*)d_in[13];
  const float* Wo  = (const float*)d_in[14];
  const float* bo  = (const float*)d_in[15];
  float* out = (float*)d_out;
  float* ws  = (float*)d_ws;

  float* keys = ws;                        // 1,048,576 f
  float* encW = keys + 1048576;            // 4,194,304 f
  float* embW = encW + 4194304;            // 2,097,152 f
  float* hs   = embW + 2097152;            //   524,288 f
  float* xch  = hs   + 524288;             //   147,456 f  (2 x 256 x 288)
  float* part = xch  + 147456;             //   512,000 f  (250 x 2048)
  unsigned* flags = (unsigned*)(part + 512000);  // 256

  hipLaunchKernelGGL(k_prep, dim3(1792), dim3(256), 0, stream,
                     enc, Wk, bk, Wx, E, tok, keys, encW, embW, flags);
  hipLaunchKernelGGL(k_recur, dim3(256), dim3(1024), 0, stream,
                     h0, c0, Wq, bq, Vw, bv, Wh, bl, keys, encW, embW,
                     hs, xch, flags);
  hipLaunchKernelGGL(k_logits, dim3(NLG), dim3(1024), 0, stream,
                     hs, Wo, bo, out, part);
  hipLaunchKernelGGL(k_scale, dim3(2048), dim3(256), 0, stream, out, part);
}